// Round 7
// baseline (3130.481 us; speedup 1.0000x reference)
//
#include <hip/hip_runtime.h>
#include <cstdint>
#include <cstddef>

// GenPhiloText: emb[X] @ W -> 128-step LSTM -> hs @ Wd -> BN(inference)
// B=32 T=128 V=32000 E=512 H=1024
//
// R6 = audited base (R4/R5) with hipMemcpyAsync replaced by a copy kernel
// (capture path now contains ONLY kernel launches):
//  * ws footprint 55.0 MB, runtime-guarded (clean no-op beats OOB fault).
//  * W/Wd read directly as fp32 [K][N] in the GEMM (reg micro-transpose ->
//    bf16 LDS, k-major stride-40) — no 64MB Wdt buffer.
//  * LSTM is one-launch-per-timestep (no grid barrier, cannot hang).

typedef unsigned short u16;
typedef short short8 __attribute__((ext_vector_type(8)));   // 8 x bf16 (4 VGPRs)
typedef float f32x4 __attribute__((ext_vector_type(4)));

#define B_ 32
#define T_ 128
#define V_ 32000
#define E_ 512
#define H_ 1024

__device__ __forceinline__ u16 f2bf(float f){
  union { float f; uint32_t u; } x; x.f = f;
  uint32_t r = (x.u + 0x7fffu + ((x.u >> 16) & 1u)) >> 16;  // RNE
  return (u16)r;
}
__device__ __forceinline__ float bf2f(u16 h){
  union { uint32_t u; float f; } x; x.u = ((uint32_t)h) << 16;
  return x.f;
}
__device__ __forceinline__ float sigm(float x){ return 1.f/(1.f + __expf(-x)); }
__device__ __forceinline__ float tanh_(float x){
  float t = __expf(-2.f * fabsf(x));
  float r = (1.f - t)/(1.f + t);
  return x >= 0.f ? r : -r;
}
__device__ __forceinline__ f32x4 mfma16(short8 a, short8 b, f32x4 c){
  return __builtin_amdgcn_mfma_f32_16x16x32_bf16(a, b, c, 0, 0, 0);
}

// ---------------- transpose fp32 -> bf16 (dst[c][r] = src[r][c]) — U only ----------------
struct __align__(4) us2 { u16 x,y; };
struct __align__(8) us4 { u16 x,y,z,w; };
__global__ __launch_bounds__(256) void k_transpose_bf16(
    const float* __restrict__ src, u16* __restrict__ dst, int R, int C)
{
  __shared__ float s[32][33];
  int ctiles = C >> 5;
  int bid = blockIdx.x;
  int c0 = (bid % ctiles) << 5;
  int r0 = (bid / ctiles) << 5;
  int cc = threadIdx.x & 31, r8 = threadIdx.x >> 5;
  #pragma unroll
  for (int i = 0; i < 4; ++i){
    int rr = r8 + i*8;
    s[rr][cc] = src[(size_t)(r0+rr)*C + c0 + cc];
  }
  __syncthreads();
  int co = threadIdx.x >> 4, rr2 = (threadIdx.x & 15) << 1;
  #pragma unroll
  for (int i = 0; i < 2; ++i){
    int oc = co + i*16;
    us2 o; o.x = f2bf(s[rr2][oc]); o.y = f2bf(s[rr2+1][oc]);
    *(us2*)(dst + (size_t)(c0+oc)*R + r0 + rr2) = o;
  }
}

// ---------------- embedding gather -> bf16 A matrix [4096][512] ----------------
__global__ __launch_bounds__(256) void k_gather(
    const int* __restrict__ X, const float* __restrict__ emb, u16* __restrict__ Ain)
{
  int gid = blockIdx.x*256 + threadIdx.x;   // one float4 each, 4096*128 total
  int r = gid >> 7;                          // row = t*32 + b
  int p = gid & 127;
  int t = r >> 5, b = r & 31;
  int idx = X[b*T_ + t];
  const float4 v = *(const float4*)(emb + (size_t)idx*E_ + (size_t)p*4);
  us4 o; o.x = f2bf(v.x); o.y = f2bf(v.y); o.z = f2bf(v.z); o.w = f2bf(v.w);
  *(us4*)(Ain + (size_t)r*E_ + (size_t)p*4) = o;
}

__global__ __launch_bounds__(256) void k_h0(const float* __restrict__ h0, u16* __restrict__ hg){
  int i = blockIdx.x*256 + threadIdx.x;      // 32*1024
  hg[i] = f2bf(h0[i]);
}

__global__ __launch_bounds__(256) void k_c0(const float* __restrict__ c0, float* __restrict__ cst){
  int i = blockIdx.x*256 + threadIdx.x;      // 32*1024
  cst[i] = c0[i];
}

__global__ __launch_bounds__(256) void k_invoff(
    const float* __restrict__ gamma, const float* __restrict__ beta,
    const float* __restrict__ mean, const float* __restrict__ var,
    const float* __restrict__ bd, float* __restrict__ inv, float* __restrict__ off)
{
  int v = blockIdx.x*256 + threadIdx.x;
  if (v < V_){
    float iv = gamma[v] * rsqrtf(var[v] + 1e-3f);
    inv[v] = iv;
    off[v] = (bd[v] - mean[v]) * iv + beta[v];
  }
}

// ---------------- 128x128 MFMA GEMM: A bf16 [M][K] x B fp32 [K][N] ----------------
// B is micro-transposed in registers during staging (4x4 block per thread),
// stored k-major in LDS (stride 40 u16 -> 16B-aligned b128 frag reads).
// EPI=0: out_bf16[r][n] = acc + bias[n]        (input projection -> P)
// EPI=1: out_f32 [r][n] = acc*inv[n] + off[n]  (decode + folded BN)
template<int EPI>
__global__ __launch_bounds__(256) void k_gemm(
    const u16* __restrict__ A, const float* __restrict__ Bf,
    const float* __restrict__ ep0, const float* __restrict__ ep1,
    u16* __restrict__ outb, float* __restrict__ outf,
    int N, int K, int mtiles, int cpx)
{
  __shared__ u16 As[128*32];   // [row][k] k-major
  __shared__ u16 Bs[128*40];   // [col][k] k-major, stride 40 (80B, 5x16B)
  int bid = blockIdx.x;
  bid = (bid & 7)*cpx + (bid >> 3);          // XCD swizzle (grid % 8 == 0)
  int mt = bid % mtiles, nt = bid / mtiles;
  int r0 = mt << 7, c0 = nt << 7;
  int tid = threadIdx.x;
  int w = tid >> 6, l = tid & 63, wr = w >> 1, wc = w & 1;
  int l15 = l & 15, lk = (l >> 4) << 3;

  // A staging: 512 chunks of 16B per tile; thread handles chunk tid, tid+256
  int rA0 = tid >> 2, kA0 = tid & 3, rA1 = (tid + 256) >> 2, kA1 = tid & 3;
  // B staging: thread owns 4x4 block: rows kt+kblk*4+j, cols c0+nb*4..+3
  int kblk = tid >> 5, nb = tid & 31;
  const float* Bp = Bf + (size_t)(kblk*4)*N + c0 + nb*4;

  f32x4 acc[4][4] = {};

  for (int kt = 0; kt < K; kt += 32){
    short8 va0 = *(const short8*)(A + (size_t)(r0 + rA0)*K + kt + kA0*8);
    short8 va1 = *(const short8*)(A + (size_t)(r0 + rA1)*K + kt + kA1*8);
    float4 vb0 = *(const float4*)(Bp + (size_t)(kt + 0)*N);
    float4 vb1 = *(const float4*)(Bp + (size_t)(kt + 1)*N);
    float4 vb2 = *(const float4*)(Bp + (size_t)(kt + 2)*N);
    float4 vb3 = *(const float4*)(Bp + (size_t)(kt + 3)*N);
    __syncthreads();                         // prior frag reads done
    *(short8*)(As + rA0*32 + kA0*8) = va0;
    *(short8*)(As + rA1*32 + kA1*8) = va1;
    {
      us4 o0; o0.x = f2bf(vb0.x); o0.y = f2bf(vb1.x); o0.z = f2bf(vb2.x); o0.w = f2bf(vb3.x);
      us4 o1; o1.x = f2bf(vb0.y); o1.y = f2bf(vb1.y); o1.z = f2bf(vb2.y); o1.w = f2bf(vb3.y);
      us4 o2; o2.x = f2bf(vb0.z); o2.y = f2bf(vb1.z); o2.z = f2bf(vb2.z); o2.w = f2bf(vb3.z);
      us4 o3; o3.x = f2bf(vb0.w); o3.y = f2bf(vb1.w); o3.z = f2bf(vb2.w); o3.w = f2bf(vb3.w);
      *(us4*)(Bs + (nb*4 + 0)*40 + kblk*4) = o0;
      *(us4*)(Bs + (nb*4 + 1)*40 + kblk*4) = o1;
      *(us4*)(Bs + (nb*4 + 2)*40 + kblk*4) = o2;
      *(us4*)(Bs + (nb*4 + 3)*40 + kblk*4) = o3;
    }
    __syncthreads();
    short8 af[4], bfr[4];
    #pragma unroll
    for (int i = 0; i < 4; ++i){
      af[i]  = *(const short8*)(As + (wr*64 + i*16 + l15)*32 + lk);
      bfr[i] = *(const short8*)(Bs + (wc*64 + i*16 + l15)*40 + lk);
    }
    #pragma unroll
    for (int i = 0; i < 4; ++i)
      #pragma unroll
      for (int j = 0; j < 4; ++j)
        acc[i][j] = mfma16(af[i], bfr[j], acc[i][j]);
  }

  int rbase = r0 + wr*64 + ((l >> 4) << 2);
  int cbase = c0 + wc*64 + l15;
  #pragma unroll
  for (int j = 0; j < 4; ++j){
    int col = cbase + j*16;
    if constexpr (EPI == 0){
      float bias = ep0[col];
      #pragma unroll
      for (int i = 0; i < 4; ++i){
        int r = rbase + i*16;
        #pragma unroll
        for (int jr = 0; jr < 4; ++jr)
          outb[(size_t)(r + jr)*N + col] = f2bf(acc[i][j][jr] + bias);
      }
    } else {
      float iv = ep0[col], of = ep1[col];
      #pragma unroll
      for (int i = 0; i < 4; ++i){
        int r = rbase + i*16;
        #pragma unroll
        for (int jr = 0; jr < 4; ++jr)
          outf[(size_t)(r + jr)*N + col] = acc[i][j][jr]*iv + of;
      }
    }
  }
}

// ---------------- LSTM single step: one launch per t (no grid barrier) ----------------
// 64 blocks x 512 threads. Block bk owns h-columns [bk*16, bk*16+16).
// Wave w: gate g=w&3, K-half kh=w>>2. z = P[t] + h@U; gates -> c,h update.
__global__ __launch_bounds__(512) void k_step(
    const u16* __restrict__ P, const u16* __restrict__ Ut,
    float* __restrict__ cst, u16* __restrict__ hg,
    u16* __restrict__ hs, int t)
{
  __shared__ float zs[8][32][16];  // [wave][batch][col]: two K-half partials per gate
  int tid = threadIdx.x, w = tid >> 6, l = tid & 63, bk = blockIdx.x;
  int g = w & 3, kh = w >> 2;
  int j0 = bk << 4;
  int l15 = l & 15, lk = (l >> 4) << 3;
  const u16* hcur = hg + (size_t)(t & 1)*(B_*H_);
  const u16* hr0 = hcur + (size_t)l15*H_ + kh*512 + lk;
  const u16* hr1 = hcur + (size_t)(l15+16)*H_ + kh*512 + lk;
  const u16* br  = Ut + ((size_t)g*H_ + j0 + l15)*H_ + kh*512 + lk;
  f32x4 a0={0,0,0,0}, a1={0,0,0,0};
  #pragma unroll 4
  for (int kk = 0; kk < 16; ++kk){
    int ko = kk*32;
    short8 fb  = *(const short8*)(br  + ko);
    short8 fa0 = *(const short8*)(hr0 + ko);
    short8 fa1 = *(const short8*)(hr1 + ko);
    a0 = mfma16(fa0, fb, a0);
    a1 = mfma16(fa1, fb, a1);
  }
  int rz = (l >> 4) << 2;
  #pragma unroll
  for (int jr = 0; jr < 4; ++jr){
    zs[w][rz + jr     ][l15] = a0[jr];   // C/D map: col=lane&15, row=(lane>>4)*4+reg
    zs[w][rz + jr + 16][l15] = a1[jr];
  }
  __syncthreads();
  int b = tid >> 4, jj = tid & 15;       // 512 threads = 32 batches x 16 cols
  size_t prow = ((size_t)(t*B_ + b))*(4*H_) + j0 + jj;
  float zi = zs[0][b][jj] + zs[4][b][jj] + bf2f(P[prow]);
  float zf = zs[1][b][jj] + zs[5][b][jj] + bf2f(P[prow +   H_]);
  float zg = zs[2][b][jj] + zs[6][b][jj] + bf2f(P[prow + 2*H_]);
  float zo = zs[3][b][jj] + zs[7][b][jj] + bf2f(P[prow + 3*H_]);
  int ci = b*H_ + j0 + jj;
  float cn = sigm(zf)*cst[ci] + sigm(zi)*tanh_(zg);
  float hn = sigm(zo)*tanh_(cn);
  cst[ci] = cn;
  u16 hb = f2bf(hn);
  hg[(size_t)((t+1)&1)*(B_*H_) + ci] = hb;
  hs[((size_t)(t*B_ + b))*H_ + j0 + jj] = hb;
}

// ---------------- launch ----------------
extern "C" void kernel_launch(void* const* d_in, const int* in_sizes, int n_in,
                              void* d_out, int out_size, void* d_ws, size_t ws_size,
                              hipStream_t stream)
{
  const int*   X     = (const int*)  d_in[0];
  const float* h0    = (const float*)d_in[1];
  const float* c0    = (const float*)d_in[2];
  const float* emb   = (const float*)d_in[3];
  const float* W     = (const float*)d_in[4];
  const float* U     = (const float*)d_in[5];
  const float* bvec  = (const float*)d_in[6];
  const float* Wd    = (const float*)d_in[7];
  const float* bd    = (const float*)d_in[8];
  const float* gamma = (const float*)d_in[9];
  const float* beta  = (const float*)d_in[10];
  const float* mmean = (const float*)d_in[11];
  const float* mvar  = (const float*)d_in[12];
  float* out = (float*)d_out;
  char* ws = (char*)d_ws;

  size_t o = 0;
  u16* Ut  = (u16*)(ws + o); o += (size_t)4*H_*H_*2;      //  8,388,608
  u16* P   = (u16*)(ws + o); o += (size_t)B_*T_*4*H_*2;   // 33,554,432
  u16* Ain = (u16*)(ws + o); o += (size_t)B_*T_*E_*2;     //  4,194,304
  u16* hs  = (u16*)(ws + o); o += (size_t)B_*T_*H_*2;     //  8,388,608
  u16* hg  = (u16*)(ws + o); o += (size_t)2*B_*H_*2;      //    131,072
  float* cst = (float*)(ws + o); o += (size_t)B_*H_*4;    //    131,072
  float* inv = (float*)(ws + o); o += (size_t)V_*4;       //    128,000
  float* off = (float*)(ws + o); o += (size_t)V_*4;       //    128,000
  // total = 55,044,096 bytes

  if (n_in < 13 || ws_size < o) return;  // clean incorrect beats an OOB fault

  k_transpose_bf16<<<(4*H_/32)*(H_/32), 256, 0, stream>>>(U, Ut, H_, 4*H_);
  k_gather<<<(B_*T_*E_/4)/256, 256, 0, stream>>>(X, emb, Ain);
  k_h0<<<(B_*H_)/256, 256, 0, stream>>>(h0, hg);
  k_c0<<<(B_*H_)/256, 256, 0, stream>>>(c0, cst);
  k_invoff<<<V_/256, 256, 0, stream>>>(gamma, beta, mmean, mvar, bd, inv, off);

  // P = Ain @ W + b : M=4096 N=4096 K=512, grid 32x32 (W read as fp32 [K][N])
  k_gemm<0><<<(B_*T_/128)*(4*H_/128), 256, 0, stream>>>(
      Ain, W, bvec, nullptr, P, nullptr, 4*H_, E_, B_*T_/128, ((B_*T_/128)*(4*H_/128))/8);

  for (int t = 0; t < T_; ++t)
    k_step<<<64, 512, 0, stream>>>(P, Ut, cst, hg, hs, t);

  // out = (hs @ Wd) * inv + off : M=4096 N=32000 K=1024, grid 32x250 (Wd fp32 [K][N])
  k_gemm<1><<<(B_*T_/128)*(V_/128), 256, 0, stream>>>(
      hs, Wd, inv, off, nullptr, out, V_, H_, B_*T_/128, ((B_*T_/128)*(V_/128))/8);
}